// Round 1
// 326.898 us; speedup vs baseline: 1.0094x; 1.0094x over previous
//
#include <hip/hip_runtime.h>

#define T_TOK 4096
#define D_DIM 1024
#define E_EXP 8
#define H_DIM 2048
#define CAP   10240  // 8192 slots + 8*256 tile padding (BM=256)
#define TILES_M 40   // CAP/256

typedef __attribute__((ext_vector_type(8))) short bf16x8;
typedef __attribute__((ext_vector_type(4))) float f32x4;

__device__ inline unsigned short f2bf(float f) {
    unsigned int u = __float_as_uint(f);
    unsigned int r = (u + 0x7fffu + ((u >> 16) & 1u)) >> 16;
    return (unsigned short)r;
}

#define GLD_LDS16(g, l)                                                        \
    __builtin_amdgcn_global_load_lds(                                          \
        (const __attribute__((address_space(1))) void*)(g),                    \
        (__attribute__((address_space(3))) void*)(l), 16, 0, 0)

// ------------- fp32 (R,C) -> bf16 transposed (C,R), per expert -------------
__global__ __launch_bounds__(256) void tcvt_kernel(const float* __restrict__ src,
                                                   unsigned short* __restrict__ dst,
                                                   int R, int C) {
    __shared__ float tile[64][65];
    size_t eo = (size_t)blockIdx.z * R * C;
    src += eo; dst += eo;
    int tx = threadIdx.x & 15, ty = threadIdx.x >> 4;
    int c0 = blockIdx.x * 64, r0 = blockIdx.y * 64;
    #pragma unroll
    for (int i = 0; i < 4; i++) {
        int row = ty + i * 16;
        float4 v = *(const float4*)&src[(size_t)(r0 + row) * C + c0 + tx * 4];
        tile[row][tx * 4 + 0] = v.x;
        tile[row][tx * 4 + 1] = v.y;
        tile[row][tx * 4 + 2] = v.z;
        tile[row][tx * 4 + 3] = v.w;
    }
    __syncthreads();
    #pragma unroll
    for (int i = 0; i < 4; i++) {
        int cc = ty + i * 16;
        int rr = tx * 4;
        ushort4 o;
        o.x = f2bf(tile[rr + 0][cc]);
        o.y = f2bf(tile[rr + 1][cc]);
        o.z = f2bf(tile[rr + 2][cc]);
        o.w = f2bf(tile[rr + 3][cc]);
        *(ushort4*)&dst[(size_t)(c0 + cc) * R + r0 + rr] = o;
    }
}

// -------- gating: logits, top-2, softmax, entropy partials + x->bf16 --------
__global__ __launch_bounds__(256) void gating_kernel(
    const float* __restrict__ xf, const float* __restrict__ wg,
    const float* __restrict__ bg, unsigned short* __restrict__ xb,
    int* __restrict__ tk_e, float* __restrict__ tk_g,
    float* __restrict__ ent_part)
{
    __shared__ float ents[4];
    int wave = threadIdx.x >> 6, lane = threadIdx.x & 63;
    int t = blockIdx.x * 4 + wave;
    const float* xr = xf + (size_t)t * D_DIM;
    unsigned short* xbr = xb + (size_t)t * D_DIM;
    float acc[8] = {0.f,0.f,0.f,0.f,0.f,0.f,0.f,0.f};
    for (int i = 0; i < 16; i++) {
        int d = lane + i * 64;
        float xv = xr[d];
        xbr[d] = f2bf(xv);
        const float4* wr = (const float4*)(wg + (size_t)d * 8);
        float4 w0 = wr[0], w1 = wr[1];
        acc[0] += xv * w0.x; acc[1] += xv * w0.y; acc[2] += xv * w0.z; acc[3] += xv * w0.w;
        acc[4] += xv * w1.x; acc[5] += xv * w1.y; acc[6] += xv * w1.z; acc[7] += xv * w1.w;
    }
    #pragma unroll
    for (int s = 1; s < 64; s <<= 1) {
        #pragma unroll
        for (int e = 0; e < 8; e++) acc[e] += __shfl_xor(acc[e], s, 64);
    }
    if (lane == 0) {
        float l[8];
        #pragma unroll
        for (int e = 0; e < 8; e++) l[e] = acc[e] + bg[e];
        int i0 = 0;
        #pragma unroll
        for (int e = 1; e < 8; e++) if (l[e] > l[i0]) i0 = e;
        int i1 = (i0 == 0) ? 1 : 0;
        #pragma unroll
        for (int e = 0; e < 8; e++) if (e != i0 && l[e] > l[i1]) i1 = e;
        float z  = expf(l[i1] - l[i0]);          // <= 1
        float p0 = 1.0f / (1.0f + z);
        float p1 = z / (1.0f + z);
        float ent = -(p0 * logf(fmaxf(p0, 1e-8f)) + p1 * logf(fmaxf(p1, 1e-8f)));
        ents[wave] = ent;
        tk_e[t * 2 + 0] = i0; tk_g[t * 2 + 0] = p0;
        tk_e[t * 2 + 1] = i1; tk_g[t * 2 + 1] = p1;
    }
    __syncthreads();
    if (threadIdx.x == 0)
        ent_part[blockIdx.x] = ents[0] + ents[1] + ents[2] + ents[3];
}

// ------- routing: count + 256-padded offsets + scatter + entropy reduce -------
__global__ __launch_bounds__(1024) void route_kernel(
    const int* __restrict__ tk_e, const float* __restrict__ tk_g,
    int* __restrict__ off, int* __restrict__ slot_token,
    float* __restrict__ slot_gate, int* __restrict__ slot_of,
    const float* __restrict__ ent_part, float* __restrict__ ent_out)
{
    __shared__ int wt[16][8];     // per-wave totals
    __shared__ int wx[16][8];     // per-wave exclusive prefix
    __shared__ int base[9];       // padded offsets
    __shared__ int tot[8];        // true counts
    __shared__ float es[16];

    int tid = threadIdx.x, wid = tid >> 6, lane = tid & 63;
    int i0 = tid * 8;
    int ev[8];
    *(int4*)&ev[0] = *(const int4*)&tk_e[i0];
    *(int4*)&ev[4] = *(const int4*)&tk_e[i0 + 4];

    float s = ent_part[tid];
    #pragma unroll
    for (int d = 1; d < 64; d <<= 1) s += __shfl_xor(s, d, 64);
    if (lane == 0) es[wid] = s;

    unsigned own[4] = {0u, 0u, 0u, 0u};
    #pragma unroll
    for (int j = 0; j < 8; j++) {
        int e = ev[j];
        int reg = ((e < 4) ? 0 : 2) + (e & 1);
        own[reg] += 1u << (((e >> 1) & 1) * 16);
    }
    unsigned inc[4] = {own[0], own[1], own[2], own[3]};
    #pragma unroll
    for (int d = 1; d < 64; d <<= 1) {
        #pragma unroll
        for (int k = 0; k < 4; k++) {
            unsigned t = __shfl_up(inc[k], d, 64);
            if (lane >= d) inc[k] += t;
        }
    }
    if (lane == 63) {
        #pragma unroll
        for (int e = 0; e < 8; e++) {
            int reg = ((e < 4) ? 0 : 2) + (e & 1);
            wt[wid][e] = (inc[reg] >> (((e >> 1) & 1) * 16)) & 0xFFFF;
        }
    }
    __syncthreads();
    if (tid == 0) {
        int o = 0;
        for (int e = 0; e < 8; e++) {
            int run = 0;
            for (int w = 0; w < 16; w++) { wx[w][e] = run; run += wt[w][e]; }
            tot[e] = run;
            base[e] = o;
            off[e] = o;
            o += (run + 255) & ~255;     // pad to BM=256
        }
        base[8] = o;
        off[8] = o;
        float se = 0.f;
        for (int w = 0; w < 16; w++) se += es[w];
        *ent_out = se * (1.0f / T_TOK);
    }
    __syncthreads();

    #pragma unroll
    for (int e = 0; e < 8; e++) {
        int p0 = base[e] + tot[e], p1 = base[e + 1];
        for (int i = p0 + tid; i < p1; i += 1024) slot_token[i] = -1;
    }

    unsigned run[4] = {0u, 0u, 0u, 0u};
    #pragma unroll
    for (int j = 0; j < 8; j++) {
        int e = ev[j];
        int reg = ((e < 4) ? 0 : 2) + (e & 1);
        int sh = ((e >> 1) & 1) * 16;
        int lx = (int)(((inc[reg] - own[reg]) >> sh) & 0xFFFF);
        int lr = (int)((run[reg] >> sh) & 0xFFFF);
        int slot = base[e] + wx[wid][e] + lx + lr;
        run[reg] += 1u << sh;
        int i = i0 + j;
        slot_token[slot] = i >> 1;
        slot_gate[slot] = tk_g[i];
        slot_of[i] = slot;
    }
}

// ---------------- 8-phase ring-4 pipelined GEMM ----------------
// BM=256, BN=128, BK=32; 512 threads = 8 waves (4M x 2N, per-wave 64x128 out).
// LDS = 4 ring units x (A 16KB + B 8KB) = 96KB. Per phase:
//   8x ds_read_b128 frags (ring t&3) | 3x global_load_lds (unit t+3 -> ring (t+3)&3)
//   s_barrier | lgkmcnt(0) | setprio(1) 16x MFMA setprio(0) | vmcnt(6) | s_barrier
// vmcnt(6) keeps 2 K-units (6 loads) in flight across barriers (T3+T4); drains
// 6->3->0 only in the last 3 phases. Swizzle: LDS chunk p holds logical p^((row>>1)&3).
template<int KD, int ND, bool GATHER, bool RELU>
__global__ __launch_bounds__(512, 2) void gemm8p_kernel(
    const unsigned short* __restrict__ Ag, const unsigned short* __restrict__ Bw,
    const float* __restrict__ bias, const int* __restrict__ off,
    const int* __restrict__ slot_token, unsigned short* __restrict__ Out)
{
    constexpr int NT = KD / 32;           // K-units
    __shared__ __align__(16) unsigned short smem[49152];   // 96 KB

    int s0 = blockIdx.x * 256;
    if (s0 >= off[E_EXP]) return;
    int e = 0;
    while (s0 >= off[e + 1]) e++;
    int n0 = blockIdx.y * 128;

    int tid = threadIdx.x;
    int w = tid >> 6, lane = tid & 63;
    int wm = w >> 1, wn = w & 1;          // 4M x 2N wave grid
    int lrow = lane & 15, q = lane >> 4;
    int lr = lane >> 2;
    int clg = ((lane & 3) ^ ((lane >> 3) & 3)) * 8;   // pre-swizzled global chunk

    // staging rows (per thread, fixed for all K-units)
    int rA0 = w * 32 + lr, rA1 = rA0 + 16;    // A rows 0..255
    int rB  = w * 16 + lr;                    // B rows 0..127

    const unsigned short* aS0;
    const unsigned short* aS1;
    if constexpr (GATHER) {
        int t0 = slot_token[s0 + rA0]; if (t0 < 0) t0 = 0;
        int t1 = slot_token[s0 + rA1]; if (t1 < 0) t1 = 0;
        aS0 = Ag + (size_t)t0 * KD + clg;
        aS1 = Ag + (size_t)t1 * KD + clg;
    } else {
        aS0 = Ag + (size_t)(s0 + rA0) * KD + clg;
        aS1 = Ag + (size_t)(s0 + rA1) * KD + clg;
    }
    const unsigned short* bS = Bw + (size_t)e * ND * KD + (size_t)(n0 + rB) * KD + clg;

    // LDS bases (shorts). Unit = 12288 shorts: A [0,8192), B [8192,12288).
    int stA = w * 1024;            // wave-uniform: rows w*32.. ; +512 -> +16 rows
    int stB = 8192 + w * 512;      // rows w*16..
    int swz = (q ^ ((lrow >> 1) & 3)) << 3;
    int aoff = (wm * 64 + lrow) * 32 + swz;
    int boff = 8192 + (wn * 64 + lrow) * 32 + swz;

    f32x4 acc[4][4];
    #pragma unroll
    for (int mi = 0; mi < 4; mi++)
        #pragma unroll
        for (int ni = 0; ni < 4; ni++) acc[mi][ni] = (f32x4){0.f, 0.f, 0.f, 0.f};

    // prologue: stage units 0,1,2 into rings 0,1,2 (9 loads), keep 6 in flight
    #pragma unroll
    for (int u = 0; u < 3; u++) {
        GLD_LDS16(aS0 + u * 32, smem + u * 12288 + stA);
        GLD_LDS16(aS1 + u * 32, smem + u * 12288 + stA + 512);
        GLD_LDS16(bS  + u * 32, smem + u * 12288 + stB);
    }
    asm volatile("s_waitcnt vmcnt(6)" ::: "memory");
    asm volatile("s_barrier" ::: "memory");

#define PHASE(RP, RS, U, DOST, VM)                                             \
    {                                                                          \
        bf16x8 af[4], bfr[4];                                                  \
        _Pragma("unroll")                                                      \
        for (int i = 0; i < 4; i++) {                                          \
            af[i]  = *(const bf16x8*)&smem[(RP) * 12288 + aoff + i * 512];     \
            bfr[i] = *(const bf16x8*)&smem[(RP) * 12288 + boff + i * 512];     \
        }                                                                      \
        if (DOST) {                                                            \
            GLD_LDS16(aS0 + (size_t)(U) * 32, smem + (RS) * 12288 + stA);      \
            GLD_LDS16(aS1 + (size_t)(U) * 32, smem + (RS) * 12288 + stA + 512);\
            GLD_LDS16(bS  + (size_t)(U) * 32, smem + (RS) * 12288 + stB);      \
        }                                                                      \
        asm volatile("s_barrier" ::: "memory");                                \
        asm volatile("s_waitcnt lgkmcnt(0)" ::: "memory");                     \
        __builtin_amdgcn_s_setprio(1);                                         \
        _Pragma("unroll")                                                      \
        for (int mi = 0; mi < 4; mi++)                                         \
            _Pragma("unroll")                                                  \
            for (int ni = 0; ni < 4; ni++)                                     \
                acc[mi][ni] = __builtin_amdgcn_mfma_f32_16x16x32_bf16(         \
                    af[mi], bfr[ni], acc[mi][ni], 0, 0, 0);                    \
        __builtin_amdgcn_s_setprio(0);                                         \
        asm volatile("s_waitcnt vmcnt(" VM ")" ::: "memory");                  \
        asm volatile("s_barrier" ::: "memory");                                \
    }

    int t4 = 0;
    for (; t4 + 8 <= NT; t4 += 4) {
        PHASE(0, 3, t4 + 3, true, "6")
        PHASE(1, 0, t4 + 4, true, "6")
        PHASE(2, 1, t4 + 5, true, "6")
        PHASE(3, 2, t4 + 6, true, "6")
    }
    // final 4 phases (t4 == NT-4): last stage, then drain 6 -> 3 -> 0
    PHASE(0, 3, t4 + 3, true,  "6")
    PHASE(1, 0, 0,      false, "3")
    PHASE(2, 1, 0,      false, "0")
    PHASE(3, 2, 0,      false, "63")
#undef PHASE

    // epilogue: bias(+relu) -> bf16, per-wave LDS repack -> 16B coalesced stores
    float bv[4];
    #pragma unroll
    for (int ni = 0; ni < 4; ni++)
        bv[ni] = bias[(size_t)e * ND + n0 + wn * 64 + ni * 16 + lrow];
    unsigned short* scr = smem + w * 1024;   // 16x64 bf16 per wave (2KB)
    #pragma unroll
    for (int mi = 0; mi < 4; mi++) {
        #pragma unroll
        for (int ni = 0; ni < 4; ni++)
            #pragma unroll
            for (int r = 0; r < 4; r++) {
                float v = acc[mi][ni][r] + bv[ni];
                if constexpr (RELU) v = fmaxf(v, 0.0f);
                scr[(q * 4 + r) * 64 + ni * 16 + lrow] = f2bf(v);
            }
        // intra-wave LDS dependency only: no barrier needed
        int rd = lane >> 3, cc = (lane & 7) * 8;
        bf16x8 v0 = *(const bf16x8*)&scr[rd * 64 + cc];
        bf16x8 v1 = *(const bf16x8*)&scr[(8 + rd) * 64 + cc];
        size_t rowg = (size_t)(s0 + wm * 64 + mi * 16 + rd) * ND + n0 + wn * 64 + cc;
        *(bf16x8*)&Out[rowg] = v0;
        *(bf16x8*)&Out[rowg + 8 * (size_t)ND] = v1;
    }
}

// ---------------- combine: out[t] = g0*Y[slot0] + g1*Y[slot1] ----------------
__global__ __launch_bounds__(256) void combine_kernel(
    const unsigned short* __restrict__ Yb, const int* __restrict__ slot_of,
    const float* __restrict__ tk_g, float* __restrict__ out)
{
    int t = blockIdx.x * 2 + (threadIdx.x >> 7);
    int j = threadIdx.x & 127;                 // 8 elements per thread
    int sA = slot_of[t * 2], sB = slot_of[t * 2 + 1];
    float gA = tk_g[t * 2], gB = tk_g[t * 2 + 1];
    uint4 va = *(const uint4*)(Yb + (size_t)sA * D_DIM + j * 8);
    uint4 vb = *(const uint4*)(Yb + (size_t)sB * D_DIM + j * 8);
    const unsigned int* pa = (const unsigned int*)&va;
    const unsigned int* pb = (const unsigned int*)&vb;
    float o[8];
    #pragma unroll
    for (int i = 0; i < 4; i++) {
        float a_lo = __uint_as_float(pa[i] << 16);
        float a_hi = __uint_as_float(pa[i] & 0xffff0000u);
        float b_lo = __uint_as_float(pb[i] << 16);
        float b_hi = __uint_as_float(pb[i] & 0xffff0000u);
        o[i * 2 + 0] = gA * a_lo + gB * b_lo;
        o[i * 2 + 1] = gA * a_hi + gB * b_hi;
    }
    float* op = out + (size_t)t * D_DIM + j * 8;
    ((float4*)op)[0] = make_float4(o[0], o[1], o[2], o[3]);
    ((float4*)op)[1] = make_float4(o[4], o[5], o[6], o[7]);
}

extern "C" void kernel_launch(void* const* d_in, const int* in_sizes, int n_in,
                              void* d_out, int out_size, void* d_ws, size_t ws_size,
                              hipStream_t stream)
{
    const float* xf = (const float*)d_in[0];
    const float* wg = (const float*)d_in[1];
    const float* bg = (const float*)d_in[2];
    const float* w1 = (const float*)d_in[3];
    const float* b1 = (const float*)d_in[4];
    const float* w2 = (const float*)d_in[5];
    const float* b2 = (const float*)d_in[6];
    float* out = (float*)d_out;

    char* p = (char*)d_ws;
    int* off    = (int*)p;                              // 16 (9 used)
    int* tk_e   = off + 16;                             // 8192
    float* tk_g = (float*)(tk_e + T_TOK * 2);           // 8192
    int* slot_token = (int*)(tk_g + T_TOK * 2);         // CAP
    float* slot_gate = (float*)(slot_token + CAP);      // CAP
    int* slot_of = (int*)(slot_gate + CAP);             // 8192
    float* ent_part = (float*)(slot_of + T_TOK * 2);    // 1024
    size_t ofs = ((size_t)((char*)(ent_part + T_TOK / 4) - p) + 255) & ~(size_t)255;
    unsigned short* xb  = (unsigned short*)(p + ofs); ofs += (size_t)T_TOK * D_DIM * 2;
    unsigned short* w1t = (unsigned short*)(p + ofs); ofs += (size_t)E_EXP * D_DIM * H_DIM * 2;
    unsigned short* w2t = (unsigned short*)(p + ofs); ofs += (size_t)E_EXP * H_DIM * D_DIM * 2;
    unsigned short* Hb  = (unsigned short*)(p + ofs); ofs += (size_t)CAP * H_DIM * 2;
    unsigned short* Yb  = w1t;   // alias: w1t is dead after gemm1

    gating_kernel<<<T_TOK / 4, 256, 0, stream>>>(xf, wg, bg, xb, tk_e, tk_g, ent_part);
    route_kernel<<<1, 1024, 0, stream>>>(tk_e, tk_g, off, slot_token, slot_gate, slot_of,
                                         ent_part, out + (size_t)T_TOK * D_DIM);
    // w1 (E, D, H) -> w1t (E, H, D)
    tcvt_kernel<<<dim3(H_DIM / 64, D_DIM / 64, E_EXP), 256, 0, stream>>>(w1, w1t, D_DIM, H_DIM);
    // w2 (E, H, D) -> w2t (E, D, H)
    tcvt_kernel<<<dim3(D_DIM / 64, H_DIM / 64, E_EXP), 256, 0, stream>>>(w2, w2t, H_DIM, D_DIM);
    // GEMM1: Hb = relu(gather(xb) @ w1t[e]^T + b1[e])
    gemm8p_kernel<D_DIM, H_DIM, true, true>
        <<<dim3(TILES_M, H_DIM / 128), 512, 0, stream>>>(xb, w1t, b1, off, slot_token, Hb);
    // GEMM2: Yb = Hb @ w2t[e]^T + b2[e]
    gemm8p_kernel<H_DIM, D_DIM, false, false>
        <<<dim3(TILES_M, D_DIM / 128), 512, 0, stream>>>(Hb, w2t, b2, off, slot_token, Yb);
    combine_kernel<<<T_TOK / 2, 256, 0, stream>>>(Yb, slot_of, tk_g, out);
}